// Round 1
// baseline (1051.794 us; speedup 1.0000x reference)
//
#include <hip/hip_runtime.h>

#define DD 128

__device__ __forceinline__ float lrelu(float x){ return x >= 0.f ? x : 0.2f*x; }

// ---------------- CSR build ----------------
__global__ void k_deg_init(int* deg, int n){
  int i = blockIdx.x*blockDim.x + threadIdx.x;
  if (i < n) deg[i] = 1; // self loop
}
__global__ void k_deg_hist(const int* __restrict__ dst, int* __restrict__ deg, int E){
  int e = blockIdx.x*blockDim.x + threadIdx.x;
  if (e < E) atomicAdd(&deg[dst[e]], 1);
}
__global__ void k_scan_partial(const int* __restrict__ deg, int* __restrict__ partial, int n){
  __shared__ int s[128];
  int i = blockIdx.x*128 + threadIdx.x;
  int v = (i < n) ? deg[i] : 0;
  s[threadIdx.x] = v; __syncthreads();
  for (int off = 64; off; off >>= 1){
    if (threadIdx.x < off) s[threadIdx.x] += s[threadIdx.x + off];
    __syncthreads();
  }
  if (threadIdx.x == 0) partial[blockIdx.x] = s[0];
}
__global__ void k_scan_top(int* partial, int nChunks){
  __shared__ int s[512];
  int v = (threadIdx.x < nChunks) ? partial[threadIdx.x] : 0;
  s[threadIdx.x] = v; __syncthreads();
  for (int off = 1; off < 512; off <<= 1){
    int t = (threadIdx.x >= (unsigned)off) ? s[threadIdx.x - off] : 0;
    __syncthreads();
    s[threadIdx.x] += t;
    __syncthreads();
  }
  if (threadIdx.x < nChunks) partial[threadIdx.x] = s[threadIdx.x] - v; // exclusive
}
__global__ void k_scan_final(const int* __restrict__ deg, const int* __restrict__ partial,
                             int* __restrict__ rowptr, int* __restrict__ wptr, int n){
  __shared__ int s[128];
  int i = blockIdx.x*128 + threadIdx.x;
  int v = (i < n) ? deg[i] : 0;
  s[threadIdx.x] = v; __syncthreads();
  for (int off = 1; off < 128; off <<= 1){
    int t = (threadIdx.x >= (unsigned)off) ? s[threadIdx.x - off] : 0;
    __syncthreads();
    s[threadIdx.x] += t;
    __syncthreads();
  }
  int excl = s[threadIdx.x] - v + partial[blockIdx.x];
  if (i < n){
    rowptr[i] = excl; wptr[i] = excl;
    if (i == n-1) rowptr[n] = excl + v;
  }
}
__global__ void k_scatter(const int* __restrict__ src, const int* __restrict__ dst,
                          int* __restrict__ wptr, int* __restrict__ col, int E, int n){
  int e = blockIdx.x*blockDim.x + threadIdx.x;
  if (e < E){
    int d = dst[e];
    int p = atomicAdd(&wptr[d], 1);
    col[p] = src[e];
  } else if (e < E + n){
    int i = e - E;
    int p = atomicAdd(&wptr[i], 1);
    col[p] = i;
  }
}

// ---------------- fused matmul (+ attention logits) ----------------
// out = hin @ W (+bias); if ATT: es[n,4], ed[n,4] per-head dot with att vectors.
template<bool ATT>
__global__ __launch_bounds__(256) void k_mm(const float* __restrict__ hin, const float* __restrict__ W,
    const float* __restrict__ bias, float* __restrict__ out,
    float* __restrict__ es, float* __restrict__ ed,
    const float* __restrict__ att_s, const float* __restrict__ att_d, int n)
{
  __shared__ float Wl[DD*DD]; // 64 KB
  for (int t = threadIdx.x; t < DD*DD; t += 256) Wl[t] = W[t];
  __syncthreads();
  const int wave = threadIdx.x >> 6, lane = threadIdx.x & 63;
  const int rowbase = blockIdx.x*64 + wave*16;
  for (int g = 0; g < 2; ++g){
    const int r0 = rowbase + g*8;
    if (r0 >= n) return;
    float ha[8], hb[8];
    #pragma unroll
    for (int r = 0; r < 8; ++r){
      int row = r0 + r;
      bool ok = row < n;
      ha[r] = ok ? hin[row*DD + lane]      : 0.f;
      hb[r] = ok ? hin[row*DD + 64 + lane] : 0.f;
    }
    float a0[8], a1[8];
    #pragma unroll
    for (int r = 0; r < 8; ++r){ a0[r] = 0.f; a1[r] = 0.f; }
    for (int k = 0; k < 64; ++k){
      float w0 = Wl[k*DD + lane], w1 = Wl[k*DD + 64 + lane];
      #pragma unroll
      for (int r = 0; r < 8; ++r){
        float hk = __shfl(ha[r], k);
        a0[r] = fmaf(hk, w0, a0[r]);
        a1[r] = fmaf(hk, w1, a1[r]);
      }
    }
    for (int k = 0; k < 64; ++k){
      float w0 = Wl[(64+k)*DD + lane], w1 = Wl[(64+k)*DD + 64 + lane];
      #pragma unroll
      for (int r = 0; r < 8; ++r){
        float hk = __shfl(hb[r], k);
        a0[r] = fmaf(hk, w0, a0[r]);
        a1[r] = fmaf(hk, w1, a1[r]);
      }
    }
    float badd0 = bias ? bias[lane]      : 0.f;
    float badd1 = bias ? bias[64 + lane] : 0.f;
    #pragma unroll
    for (int r = 0; r < 8; ++r){
      int row = r0 + r;
      if (row >= n) break;
      out[row*DD + lane]      = a0[r] + badd0;
      out[row*DD + 64 + lane] = a1[r] + badd1;
      if (ATT){
        float ps0 = a0[r]*att_s[lane],    ps1 = a1[r]*att_s[64+lane];
        float pd0 = a0[r]*att_d[lane],    pd1 = a1[r]*att_d[64+lane];
        #pragma unroll
        for (int off = 1; off < 32; off <<= 1){
          ps0 += __shfl_xor(ps0, off); ps1 += __shfl_xor(ps1, off);
          pd0 += __shfl_xor(pd0, off); pd1 += __shfl_xor(pd1, off);
        }
        if ((lane & 31) == 0){
          int hh = lane >> 5; // 0 or 1
          es[row*4 + hh]     = ps0; es[row*4 + 2 + hh] = ps1;
          ed[row*4 + hh]     = pd0; ed[row*4 + 2 + hh] = pd1;
        }
      }
    }
  }
}

// ---------------- fused aggregation + softmax + bias + LN + relu + residual ----------------
__global__ __launch_bounds__(256) void k_agg(const float* __restrict__ xh, const float* __restrict__ es,
    const float* __restrict__ ed, const int* __restrict__ rowptr, const int* __restrict__ col,
    const float* __restrict__ cb, const float* __restrict__ lg, const float* __restrict__ lb,
    float* __restrict__ h, int n)
{
  int wid = (blockIdx.x * blockDim.x + threadIdx.x) >> 6;
  int lane = threadIdx.x & 63;
  if (wid >= n) return;
  const int i = wid;
  const int rs = rowptr[i], re = rowptr[i+1];
  const float4 edv = *reinterpret_cast<const float4*>(ed + i*4);
  // pass 1: segment max per head (lane-parallel)
  float m0 = -3.4e38f, m1 = -3.4e38f, m2 = -3.4e38f, m3 = -3.4e38f;
  for (int j = rs + lane; j < re; j += 64){
    int s = col[j];
    float4 ev = *reinterpret_cast<const float4*>(es + s*4);
    m0 = fmaxf(m0, lrelu(ev.x + edv.x));
    m1 = fmaxf(m1, lrelu(ev.y + edv.y));
    m2 = fmaxf(m2, lrelu(ev.z + edv.z));
    m3 = fmaxf(m3, lrelu(ev.w + edv.w));
  }
  #pragma unroll
  for (int off = 1; off < 64; off <<= 1){
    m0 = fmaxf(m0, __shfl_xor(m0, off));
    m1 = fmaxf(m1, __shfl_xor(m1, off));
    m2 = fmaxf(m2, __shfl_xor(m2, off));
    m3 = fmaxf(m3, __shfl_xor(m3, off));
  }
  // pass 2: serial over edges, lanes own output dims (lane, lane+64)
  const int hsel = lane >> 5;
  float acc0 = 0.f, acc1 = 0.f;
  float z0 = 0.f, z1 = 0.f, z2 = 0.f, z3 = 0.f;
  for (int j = rs; j < re; ++j){
    int s = col[j];
    float4 ev = *reinterpret_cast<const float4*>(es + s*4);
    float w0 = __expf(lrelu(ev.x + edv.x) - m0);
    float w1 = __expf(lrelu(ev.y + edv.y) - m1);
    float w2 = __expf(lrelu(ev.z + edv.z) - m2);
    float w3 = __expf(lrelu(ev.w + edv.w) - m3);
    z0 += w0; z1 += w1; z2 += w2; z3 += w3;
    float xa = xh[s*DD + lane];
    float xb = xh[s*DD + 64 + lane];
    float wa = hsel ? w1 : w0;
    float wb = hsel ? w3 : w2;
    acc0 = fmaf(xa, wa, acc0);
    acc1 = fmaf(xb, wb, acc1);
  }
  float za = hsel ? z1 : z0, zb = hsel ? z3 : z2;
  float c0 = acc0/za + cb[lane];
  float c1 = acc1/zb + cb[64+lane];
  // LayerNorm over 128 dims (2 per lane)
  float sum = c0 + c1, sq = c0*c0 + c1*c1;
  #pragma unroll
  for (int off = 1; off < 64; off <<= 1){
    sum += __shfl_xor(sum, off);
    sq  += __shfl_xor(sq,  off);
  }
  float mu  = sum * (1.f/128.f);
  float var = sq  * (1.f/128.f) - mu*mu;
  float rinv = rsqrtf(var + 1e-5f);
  float y0 = (c0 - mu)*rinv*lg[lane]    + lb[lane];
  float y1 = (c1 - mu)*rinv*lg[64+lane] + lb[64+lane];
  float r0v = h[i*DD + lane], r1v = h[i*DD + 64 + lane];
  h[i*DD + lane]      = fmaxf(y0, 0.f) + r0v;
  h[i*DD + 64 + lane] = fmaxf(y1, 0.f) + r1v;
}

// ---------------- pooling (batch is sorted) ----------------
__global__ void k_pool(const float* __restrict__ h, const int* __restrict__ batch,
                       float* __restrict__ pooled, float* __restrict__ cnt, int n){
  int d = threadIdx.x; // 128 threads
  int n0 = blockIdx.x * 256;
  int n1 = min(n0 + 256, n);
  float acc = 0.f, cacc = 0.f; int cur = -1;
  for (int i = n0; i < n1; ++i){
    int g = batch[i];
    if (g != cur){
      if (cur >= 0){
        atomicAdd(&pooled[cur*DD + d], acc);
        if (d == 0) atomicAdd(&cnt[cur], cacc);
      }
      acc = 0.f; cacc = 0.f; cur = g;
    }
    acc += h[i*DD + d];
    cacc += 1.f;
  }
  if (cur >= 0){
    atomicAdd(&pooled[cur*DD + d], acc);
    if (d == 0) atomicAdd(&cnt[cur], cacc);
  }
}

// ---------------- final MLP: relu(pooled@W1+b1)@W2+b2 ----------------
__global__ void k_mlp(const float* __restrict__ pooled, const float* __restrict__ cnt,
                      const float* __restrict__ W1, const float* __restrict__ b1,
                      const float* __restrict__ W2, const float* __restrict__ b2,
                      float* __restrict__ out, int G_){
  int g = blockIdx.x, lane = threadIdx.x; // 64 threads
  float inv = 1.f / fmaxf(cnt[g], 1.f);
  float acc = b1[lane];
  for (int k = 0; k < DD; ++k)
    acc = fmaf(pooled[g*DD + k]*inv, W1[k*64 + lane], acc);
  float hv = fmaxf(acc, 0.f) * W2[lane];
  #pragma unroll
  for (int off = 32; off; off >>= 1) hv += __shfl_down(hv, off);
  if (lane == 0) out[g] = hv + b2[0];
}

extern "C" void kernel_launch(void* const* d_in, const int* in_sizes, int n_in,
                              void* d_out, int out_size, void* d_ws, size_t ws_size,
                              hipStream_t stream){
  const float* x       = (const float*)d_in[0];
  const int*   ei      = (const int*)d_in[1];
  const int*   batch   = (const int*)d_in[2];
  const float* W_in    = (const float*)d_in[3];
  const float* b_in    = (const float*)d_in[4];
  const float* lin_W   = (const float*)d_in[5];
  const float* att_src = (const float*)d_in[6];
  const float* att_dst = (const float*)d_in[7];
  const float* conv_b  = (const float*)d_in[8];
  const float* ln_g    = (const float*)d_in[9];
  const float* ln_b    = (const float*)d_in[10];
  const float* W1      = (const float*)d_in[11];
  const float* b1      = (const float*)d_in[12];
  const float* W2      = (const float*)d_in[13];
  const float* b2      = (const float*)d_in[14];
  float* outp = (float*)d_out;

  const int N = in_sizes[0] / DD;
  const int E = in_sizes[1] / 2;
  const int G = out_size;
  const int L = 3;
  const int* srcp = ei;
  const int* dstp = ei + E;

  size_t off = 0;
  auto alloc = [&](size_t bytes) -> void* {
    void* p = (char*)d_ws + off;
    off += (bytes + 255) & ~(size_t)255;
    return p;
  };
  float* h      = (float*)alloc((size_t)N*DD*4);
  float* xh     = (float*)alloc((size_t)N*DD*4);
  float* es     = (float*)alloc((size_t)N*4*4);
  float* ed     = (float*)alloc((size_t)N*4*4);
  int*   deg    = (int*)  alloc((size_t)N*4);
  int*   rowptr = (int*)  alloc((size_t)(N+1)*4);
  int*   wptr   = (int*)  alloc((size_t)(N+1)*4);
  int*   col    = (int*)  alloc((size_t)(E+N)*4);
  int*   partial= (int*)  alloc(512*4);
  float* pooled = (float*)alloc((size_t)G*DD*4);
  float* cnt    = (float*)alloc((size_t)G*4);

  const int nChunks = (N + 127)/128;

  // CSR build (graph identical every call, rebuilt per call for capture-safety)
  k_deg_init<<<(N+255)/256, 256, 0, stream>>>(deg, N);
  k_deg_hist<<<(E+255)/256, 256, 0, stream>>>(dstp, deg, E);
  k_scan_partial<<<nChunks, 128, 0, stream>>>(deg, partial, N);
  k_scan_top<<<1, 512, 0, stream>>>(partial, nChunks);
  k_scan_final<<<nChunks, 128, 0, stream>>>(deg, partial, rowptr, wptr, N);
  k_scatter<<<(E+N+255)/256, 256, 0, stream>>>(srcp, dstp, wptr, col, E, N);

  // input projection
  k_mm<false><<<(N+63)/64, 256, 0, stream>>>(x, W_in, b_in, h,
                                             nullptr, nullptr, nullptr, nullptr, N);
  // layers
  for (int l = 0; l < L; ++l){
    k_mm<true><<<(N+63)/64, 256, 0, stream>>>(h, lin_W + (size_t)l*DD*DD, nullptr, xh, es, ed,
                                              att_src + l*DD, att_dst + l*DD, N);
    k_agg<<<(N+3)/4, 256, 0, stream>>>(xh, es, ed, rowptr, col,
                                       conv_b + l*DD, ln_g + l*DD, ln_b + l*DD, h, N);
  }

  // pooling + MLP
  hipMemsetAsync(pooled, 0, (size_t)G*DD*4, stream);
  hipMemsetAsync(cnt,    0, (size_t)G*4,    stream);
  k_pool<<<(N+255)/256, 128, 0, stream>>>(h, batch, pooled, cnt, N);
  k_mlp<<<G, 64, 0, stream>>>(pooled, cnt, W1, b1, W2, b2, outp, G);
}

// Round 2
// 731.604 us; speedup vs baseline: 1.4377x; 1.4377x over previous
//
#include <hip/hip_runtime.h>

#define DD 128

__device__ __forceinline__ float lrelu(float x){ return x >= 0.f ? x : 0.2f*x; }

// ---------------- CSR build ----------------
__global__ void k_deg_init(int* deg, int n){
  int i = blockIdx.x*blockDim.x + threadIdx.x;
  if (i < n) deg[i] = 1; // self loop
}
__global__ void k_deg_hist(const int* __restrict__ dst, int* __restrict__ deg, int E){
  int e = blockIdx.x*blockDim.x + threadIdx.x;
  if (e < E) atomicAdd(&deg[dst[e]], 1);
}
__global__ void k_scan_partial(const int* __restrict__ deg, int* __restrict__ partial, int n){
  __shared__ int s[128];
  int i = blockIdx.x*128 + threadIdx.x;
  int v = (i < n) ? deg[i] : 0;
  s[threadIdx.x] = v; __syncthreads();
  for (int off = 64; off; off >>= 1){
    if (threadIdx.x < off) s[threadIdx.x] += s[threadIdx.x + off];
    __syncthreads();
  }
  if (threadIdx.x == 0) partial[blockIdx.x] = s[0];
}
__global__ void k_scan_top(int* partial, int nChunks){
  __shared__ int s[512];
  int v = (threadIdx.x < nChunks) ? partial[threadIdx.x] : 0;
  s[threadIdx.x] = v; __syncthreads();
  for (int off = 1; off < 512; off <<= 1){
    int t = (threadIdx.x >= (unsigned)off) ? s[threadIdx.x - off] : 0;
    __syncthreads();
    s[threadIdx.x] += t;
    __syncthreads();
  }
  if (threadIdx.x < nChunks) partial[threadIdx.x] = s[threadIdx.x] - v; // exclusive
}
__global__ void k_scan_final(const int* __restrict__ deg, const int* __restrict__ partial,
                             int* __restrict__ rowptr, int* __restrict__ wptr, int n){
  __shared__ int s[128];
  int i = blockIdx.x*128 + threadIdx.x;
  int v = (i < n) ? deg[i] : 0;
  s[threadIdx.x] = v; __syncthreads();
  for (int off = 1; off < 128; off <<= 1){
    int t = (threadIdx.x >= (unsigned)off) ? s[threadIdx.x - off] : 0;
    __syncthreads();
    s[threadIdx.x] += t;
    __syncthreads();
  }
  int excl = s[threadIdx.x] - v + partial[blockIdx.x];
  if (i < n){
    rowptr[i] = excl; wptr[i] = excl;
    if (i == n-1) rowptr[n] = excl + v;
  }
}
__global__ void k_scatter(const int* __restrict__ src, const int* __restrict__ dst,
                          int* __restrict__ wptr, int* __restrict__ col, int E, int n){
  int e = blockIdx.x*blockDim.x + threadIdx.x;
  if (e < E){
    int d = dst[e];
    int p = atomicAdd(&wptr[d], 1);
    col[p] = src[e];
  } else if (e < E + n){
    int i = e - E;
    int p = atomicAdd(&wptr[i], 1);
    col[p] = i;
  }
}

// ---------------- fused matmul (+ attention logits, head-major es/ed) ----------------
// Layout: c = tid&31 owns cols 4c..4c+3 (all in head c>>3); rg = tid>>5 owns rows rg*8..+8.
// h tile (64 rows) staged in LDS (32KB); W read from global (L1/L2-resident).
template<bool ATT>
__global__ __launch_bounds__(256) void k_mm(const float* __restrict__ hin, const float* __restrict__ W,
    const float* __restrict__ bias, float* __restrict__ out,
    float* __restrict__ es, float* __restrict__ ed,
    const float* __restrict__ att_s, const float* __restrict__ att_d, int n, int N)
{
  __shared__ float hs[64*DD]; // 32 KB
  const int tid = threadIdx.x;
  const int row0 = blockIdx.x*64;
  for (int idx = tid; idx < 64*32; idx += 256){
    int r = idx >> 5, cc = (idx & 31)*4;
    int row = row0 + r;
    float4 v = (row < n) ? *(const float4*)(hin + (size_t)row*DD + cc)
                         : make_float4(0.f,0.f,0.f,0.f);
    *(float4*)(hs + r*DD + cc) = v;
  }
  __syncthreads();
  const int c  = tid & 31;
  const int rg = tid >> 5;
  float4 acc[8];
  #pragma unroll
  for (int r = 0; r < 8; ++r) acc[r] = make_float4(0.f,0.f,0.f,0.f);
  const float* hrow = hs + rg*8*DD;
  const float* wp   = W + 4*c;
  #pragma unroll 2
  for (int kk = 0; kk < DD; kk += 4){
    float4 hv[8];
    #pragma unroll
    for (int r = 0; r < 8; ++r) hv[r] = *(const float4*)(hrow + r*DD + kk);
    #pragma unroll
    for (int q = 0; q < 4; ++q){
      const float4 wv = *(const float4*)(wp + (kk+q)*DD);
      #pragma unroll
      for (int r = 0; r < 8; ++r){
        float hk = (q==0)?hv[r].x : (q==1)?hv[r].y : (q==2)?hv[r].z : hv[r].w;
        acc[r].x = fmaf(hk, wv.x, acc[r].x);
        acc[r].y = fmaf(hk, wv.y, acc[r].y);
        acc[r].z = fmaf(hk, wv.z, acc[r].z);
        acc[r].w = fmaf(hk, wv.w, acc[r].w);
      }
    }
  }
  float4 bv = make_float4(0.f,0.f,0.f,0.f);
  if (bias) bv = *(const float4*)(bias + 4*c);
  float4 as4 = make_float4(0.f,0.f,0.f,0.f), ad4 = as4;
  if (ATT){
    as4 = *(const float4*)(att_s + 4*c);
    ad4 = *(const float4*)(att_d + 4*c);
  }
  #pragma unroll
  for (int r = 0; r < 8; ++r){
    int row = row0 + rg*8 + r;
    if (row >= n) break;
    float4 o = acc[r];
    o.x += bv.x; o.y += bv.y; o.z += bv.z; o.w += bv.w;
    *(float4*)(out + (size_t)row*DD + 4*c) = o;
    if (ATT){
      float ps = o.x*as4.x + o.y*as4.y + o.z*as4.z + o.w*as4.w;
      float pd = o.x*ad4.x + o.y*ad4.y + o.z*ad4.z + o.w*ad4.w;
      ps += __shfl_xor(ps,1); ps += __shfl_xor(ps,2); ps += __shfl_xor(ps,4);
      pd += __shfl_xor(pd,1); pd += __shfl_xor(pd,2); pd += __shfl_xor(pd,4);
      if ((tid & 7) == 0){
        int hh = c >> 3;
        es[(size_t)hh*N + row] = ps;
        ed[(size_t)hh*N + row] = pd;
      }
    }
  }
}

// ---------------- fused aggregation + softmax + bias + LN + relu + residual ----------------
// 1 wave per destination node. Lane owns dims 2*lane, 2*lane+1 (head lane>>4).
__global__ __launch_bounds__(256) void k_agg(const float* __restrict__ xh, const float* __restrict__ es,
    const float* __restrict__ ed, const int* __restrict__ rowptr, const int* __restrict__ col,
    const float* __restrict__ cb, const float* __restrict__ lg, const float* __restrict__ lb,
    float* __restrict__ h, int n, int N)
{
  int wid = (blockIdx.x * blockDim.x + threadIdx.x) >> 6;
  int lane = threadIdx.x & 63;
  if (wid >= n) return;
  const int i = wid;
  const int rs = rowptr[i], re = rowptr[i+1];
  const int hsel = lane >> 4;
  const float* esh = es + (size_t)hsel*N;
  const float edd = ed[(size_t)hsel*N + i];
  // pass 1: per-head segment max (16 lanes per head, stride 16 covers all edges)
  float m = -3.4e38f;
  for (int j = rs + (lane & 15); j < re; j += 16)
    m = fmaxf(m, lrelu(esh[col[j]] + edd));
  m = fmaxf(m, __shfl_xor(m,1));
  m = fmaxf(m, __shfl_xor(m,2));
  m = fmaxf(m, __shfl_xor(m,4));
  m = fmaxf(m, __shfl_xor(m,8));
  // pass 2: serial over edges; lane accumulates its 2 dims + its head's z
  float z = 0.f;
  float2 acc = make_float2(0.f,0.f);
  for (int j = rs; j < re; ++j){
    int s = col[j];
    float w = __expf(lrelu(esh[s] + edd) - m);
    z += w;
    float2 xa = *(const float2*)(xh + (size_t)s*DD + 2*lane);
    acc.x = fmaf(xa.x, w, acc.x);
    acc.y = fmaf(xa.y, w, acc.y);
  }
  float zi = 1.f / z;
  float2 cbv = *(const float2*)(cb + 2*lane);
  float c0 = acc.x*zi + cbv.x;
  float c1 = acc.y*zi + cbv.y;
  // LayerNorm over 128 dims (2 per lane)
  float sum = c0 + c1, sq = c0*c0 + c1*c1;
  #pragma unroll
  for (int off = 1; off < 64; off <<= 1){
    sum += __shfl_xor(sum, off);
    sq  += __shfl_xor(sq,  off);
  }
  float mu  = sum * (1.f/128.f);
  float var = sq  * (1.f/128.f) - mu*mu;
  float rinv = rsqrtf(var + 1e-5f);
  float2 lgv = *(const float2*)(lg + 2*lane);
  float2 lbv = *(const float2*)(lb + 2*lane);
  float y0 = (c0 - mu)*rinv*lgv.x + lbv.x;
  float y1 = (c1 - mu)*rinv*lgv.y + lbv.y;
  float2 rv = *(const float2*)(h + (size_t)i*DD + 2*lane);
  float2 o;
  o.x = fmaxf(y0, 0.f) + rv.x;
  o.y = fmaxf(y1, 0.f) + rv.y;
  *(float2*)(h + (size_t)i*DD + 2*lane) = o;
}

// ---------------- pooling (batch is sorted) ----------------
__global__ void k_pool(const float* __restrict__ h, const int* __restrict__ batch,
                       float* __restrict__ pooled, float* __restrict__ cnt, int n){
  int d = threadIdx.x; // 128 threads
  int n0 = blockIdx.x * 256;
  int n1 = min(n0 + 256, n);
  float acc = 0.f, cacc = 0.f; int cur = -1;
  for (int i = n0; i < n1; ++i){
    int g = batch[i];
    if (g != cur){
      if (cur >= 0){
        atomicAdd(&pooled[cur*DD + d], acc);
        if (d == 0) atomicAdd(&cnt[cur], cacc);
      }
      acc = 0.f; cacc = 0.f; cur = g;
    }
    acc += h[i*DD + d];
    cacc += 1.f;
  }
  if (cur >= 0){
    atomicAdd(&pooled[cur*DD + d], acc);
    if (d == 0) atomicAdd(&cnt[cur], cacc);
  }
}

// ---------------- final MLP: relu(pooled@W1+b1)@W2+b2 ----------------
__global__ void k_mlp(const float* __restrict__ pooled, const float* __restrict__ cnt,
                      const float* __restrict__ W1, const float* __restrict__ b1,
                      const float* __restrict__ W2, const float* __restrict__ b2,
                      float* __restrict__ out, int G_){
  int g = blockIdx.x, lane = threadIdx.x; // 64 threads
  float inv = 1.f / fmaxf(cnt[g], 1.f);
  float acc = b1[lane];
  for (int k = 0; k < DD; ++k)
    acc = fmaf(pooled[g*DD + k]*inv, W1[k*64 + lane], acc);
  float hv = fmaxf(acc, 0.f) * W2[lane];
  #pragma unroll
  for (int off = 32; off; off >>= 1) hv += __shfl_down(hv, off);
  if (lane == 0) out[g] = hv + b2[0];
}

extern "C" void kernel_launch(void* const* d_in, const int* in_sizes, int n_in,
                              void* d_out, int out_size, void* d_ws, size_t ws_size,
                              hipStream_t stream){
  const float* x       = (const float*)d_in[0];
  const int*   ei      = (const int*)d_in[1];
  const int*   batch   = (const int*)d_in[2];
  const float* W_in    = (const float*)d_in[3];
  const float* b_in    = (const float*)d_in[4];
  const float* lin_W   = (const float*)d_in[5];
  const float* att_src = (const float*)d_in[6];
  const float* att_dst = (const float*)d_in[7];
  const float* conv_b  = (const float*)d_in[8];
  const float* ln_g    = (const float*)d_in[9];
  const float* ln_b    = (const float*)d_in[10];
  const float* W1      = (const float*)d_in[11];
  const float* b1      = (const float*)d_in[12];
  const float* W2      = (const float*)d_in[13];
  const float* b2      = (const float*)d_in[14];
  float* outp = (float*)d_out;

  const int N = in_sizes[0] / DD;
  const int E = in_sizes[1] / 2;
  const int G = out_size;
  const int L = 3;
  const int* srcp = ei;
  const int* dstp = ei + E;

  size_t off = 0;
  auto alloc = [&](size_t bytes) -> void* {
    void* p = (char*)d_ws + off;
    off += (bytes + 255) & ~(size_t)255;
    return p;
  };
  float* h      = (float*)alloc((size_t)N*DD*4);
  float* xh     = (float*)alloc((size_t)N*DD*4);
  float* es     = (float*)alloc((size_t)N*4*4);   // head-major [4][N]
  float* ed     = (float*)alloc((size_t)N*4*4);   // head-major [4][N]
  int*   deg    = (int*)  alloc((size_t)N*4);
  int*   rowptr = (int*)  alloc((size_t)(N+1)*4);
  int*   wptr   = (int*)  alloc((size_t)(N+1)*4);
  int*   col    = (int*)  alloc((size_t)(E+N)*4);
  int*   partial= (int*)  alloc(512*4);
  float* pooled = (float*)alloc((size_t)G*DD*4);
  float* cnt    = (float*)alloc((size_t)G*4);

  const int nChunks = (N + 127)/128;

  // CSR build (graph identical every call, rebuilt per call for capture-safety)
  k_deg_init<<<(N+255)/256, 256, 0, stream>>>(deg, N);
  k_deg_hist<<<(E+255)/256, 256, 0, stream>>>(dstp, deg, E);
  k_scan_partial<<<nChunks, 128, 0, stream>>>(deg, partial, N);
  k_scan_top<<<1, 512, 0, stream>>>(partial, nChunks);
  k_scan_final<<<nChunks, 128, 0, stream>>>(deg, partial, rowptr, wptr, N);
  k_scatter<<<(E+N+255)/256, 256, 0, stream>>>(srcp, dstp, wptr, col, E, N);

  // input projection
  k_mm<false><<<(N+63)/64, 256, 0, stream>>>(x, W_in, b_in, h,
                                             nullptr, nullptr, nullptr, nullptr, N, N);
  // layers
  for (int l = 0; l < L; ++l){
    k_mm<true><<<(N+63)/64, 256, 0, stream>>>(h, lin_W + (size_t)l*DD*DD, nullptr, xh, es, ed,
                                              att_src + l*DD, att_dst + l*DD, N, N);
    k_agg<<<(N+3)/4, 256, 0, stream>>>(xh, es, ed, rowptr, col,
                                       conv_b + l*DD, ln_g + l*DD, ln_b + l*DD, h, N, N);
  }

  // pooling + MLP
  hipMemsetAsync(pooled, 0, (size_t)G*DD*4, stream);
  hipMemsetAsync(cnt,    0, (size_t)G*4,    stream);
  k_pool<<<(N+255)/256, 128, 0, stream>>>(h, batch, pooled, cnt, N);
  k_mlp<<<G, 64, 0, stream>>>(pooled, cnt, W1, b1, W2, b2, outp, G);
}

// Round 5
// 570.503 us; speedup vs baseline: 1.8436x; 1.2824x over previous
//
#include <hip/hip_runtime.h>

#define DD 128

typedef __bf16 bf16x8 __attribute__((ext_vector_type(8)));
typedef float  f32x4  __attribute__((ext_vector_type(4)));

__device__ __forceinline__ float lrelu(float x){ return x >= 0.f ? x : 0.2f*x; }
__device__ __forceinline__ float bflo(unsigned u){ return __uint_as_float(u << 16); }
__device__ __forceinline__ float bfhi(unsigned u){ return __uint_as_float(u & 0xffff0000u); }
__device__ __forceinline__ float red16(float v){
  v += __shfl_xor(v,1); v += __shfl_xor(v,2);
  v += __shfl_xor(v,4); v += __shfl_xor(v,8);
  return v;
}

// ---------------- CSR build ----------------
__global__ void k_deg_init(int* deg, int n){
  int i = blockIdx.x*blockDim.x + threadIdx.x;
  if (i < n) deg[i] = 1; // self loop
}
__global__ void k_deg_hist(const int* __restrict__ dst, int* __restrict__ deg, int E){
  int e = blockIdx.x*blockDim.x + threadIdx.x;
  if (e < E) atomicAdd(&deg[dst[e]], 1);
}
__global__ void k_scan_partial(const int* __restrict__ deg, int* __restrict__ partial, int n){
  __shared__ int s[128];
  int i = blockIdx.x*128 + threadIdx.x;
  int v = (i < n) ? deg[i] : 0;
  s[threadIdx.x] = v; __syncthreads();
  for (int off = 64; off; off >>= 1){
    if (threadIdx.x < off) s[threadIdx.x] += s[threadIdx.x + off];
    __syncthreads();
  }
  if (threadIdx.x == 0) partial[blockIdx.x] = s[0];
}
__global__ void k_scan_top(int* partial, int nChunks){
  __shared__ int s[512];
  int v = (threadIdx.x < nChunks) ? partial[threadIdx.x] : 0;
  s[threadIdx.x] = v; __syncthreads();
  for (int off = 1; off < 512; off <<= 1){
    int t = (threadIdx.x >= (unsigned)off) ? s[threadIdx.x - off] : 0;
    __syncthreads();
    s[threadIdx.x] += t;
    __syncthreads();
  }
  if (threadIdx.x < nChunks) partial[threadIdx.x] = s[threadIdx.x] - v; // exclusive
}
__global__ void k_scan_final(const int* __restrict__ deg, const int* __restrict__ partial,
                             int* __restrict__ rowptr, int* __restrict__ wptr, int n){
  __shared__ int s[128];
  int i = blockIdx.x*128 + threadIdx.x;
  int v = (i < n) ? deg[i] : 0;
  s[threadIdx.x] = v; __syncthreads();
  for (int off = 1; off < 128; off <<= 1){
    int t = (threadIdx.x >= (unsigned)off) ? s[threadIdx.x - off] : 0;
    __syncthreads();
    s[threadIdx.x] += t;
    __syncthreads();
  }
  int excl = s[threadIdx.x] - v + partial[blockIdx.x];
  if (i < n){
    rowptr[i] = excl; wptr[i] = excl;
    if (i == n-1) rowptr[n] = excl + v;
  }
}
__global__ void k_scatter(const int* __restrict__ src, const int* __restrict__ dst,
                          int* __restrict__ wptr, int* __restrict__ col, int E, int n){
  int e = blockIdx.x*blockDim.x + threadIdx.x;
  if (e < E){
    int d = dst[e];
    int p = atomicAdd(&wptr[d], 1);
    col[p] = src[e];
  } else if (e < E + n){
    int i = e - E;
    int p = atomicAdd(&wptr[i], 1);
    col[p] = i;
  }
}

// ---------------- weight prep: bf16 hi/lo col-major (B^T) for MFMA ----------------
// matrix m (0=W_in, 1..3=lin_W[l]): hi plane at (2m)*DD*DD, lo plane at (2m+1)*DD*DD
// layout within plane: [c][k]
__global__ void k_wprep(const float* __restrict__ Win, const float* __restrict__ linW,
                        __bf16* __restrict__ wt){
  int idx = blockIdx.x*256 + threadIdx.x;     // 4 * 16384 threads
  int m = idx >> 14, r = idx & 16383;
  int k = r >> 7, c = r & 127;
  const float* src = (m == 0) ? Win : linW + (size_t)(m-1)*DD*DD;
  float w = src[(size_t)k*DD + c];
  __bf16 hi = (__bf16)w;
  __bf16 lo = (__bf16)(w - (float)hi);
  wt[(size_t)(2*m  )*DD*DD + (size_t)c*DD + k] = hi;
  wt[(size_t)(2*m+1)*DD*DD + (size_t)c*DD + k] = lo;
}

// ---------------- MFMA matmul (3-term hi/lo): out = hin @ W (+bias) ----------------
// Wave computes 16 rows x 64 cols. A: row=l&15, k=(l>>4)*8+reg (+32*kc).
// B: col=l&15, k contiguous. C: col=lane&15, row=(lane>>4)*4+reg.
// If !OUTF32: also emit per-head attention logits from fp32 accumulators.
template<int OUTF32>
__global__ __launch_bounds__(256) void k_mm_mfma(const float* __restrict__ hin,
    const __bf16* __restrict__ Wt, const float* __restrict__ bias,
    float* __restrict__ outf, __bf16* __restrict__ outb,
    const float* __restrict__ att_s, const float* __restrict__ att_d,
    float* __restrict__ es, float* __restrict__ ed, int n, int N)
{
  const int tid = threadIdx.x;
  const int wv  = tid >> 6, l = tid & 63;
  const int lr = l & 15, lk = l >> 4;
  const int row0 = blockIdx.x*32 + (wv >> 1)*16;
  const int ct0  = (wv & 1)*4;
  int arow = row0 + lr; if (arow >= n) arow = n - 1;
  const float* hp = hin + (size_t)arow*DD + lk*8;
  bf16x8 ah[4], al[4];
  #pragma unroll
  for (int kc = 0; kc < 4; ++kc){
    float4 lo4 = *(const float4*)(hp + kc*32);
    float4 hi4 = *(const float4*)(hp + kc*32 + 4);
    float vv[8] = {lo4.x,lo4.y,lo4.z,lo4.w,hi4.x,hi4.y,hi4.z,hi4.w};
    bf16x8 vh, vl;
    #pragma unroll
    for (int q = 0; q < 8; ++q){
      __bf16 h = (__bf16)vv[q];
      vh[q] = h;
      vl[q] = (__bf16)(vv[q] - (float)h);
    }
    ah[kc] = vh; al[kc] = vl;
  }
  f32x4 acc[4];
  #pragma unroll
  for (int ct = 0; ct < 4; ++ct) acc[ct] = (f32x4){0.f,0.f,0.f,0.f};
  const __bf16* wp = Wt + (size_t)lr*DD + lk*8;
  #pragma unroll
  for (int ct = 0; ct < 4; ++ct){
    const __bf16* wpc = wp + (size_t)(ct0+ct)*16*DD;
    #pragma unroll
    for (int kc = 0; kc < 4; ++kc){
      bf16x8 bh = *(const bf16x8*)(wpc + (size_t)kc*32);
      bf16x8 bl = *(const bf16x8*)(wpc + DD*DD + (size_t)kc*32);
      acc[ct] = __builtin_amdgcn_mfma_f32_16x16x32_bf16(ah[kc], bh, acc[ct], 0, 0, 0);
      acc[ct] = __builtin_amdgcn_mfma_f32_16x16x32_bf16(al[kc], bh, acc[ct], 0, 0, 0);
      acc[ct] = __builtin_amdgcn_mfma_f32_16x16x32_bf16(ah[kc], bl, acc[ct], 0, 0, 0);
    }
  }
  const int orow0 = row0 + lk*4;
  // store outputs
  #pragma unroll
  for (int ct = 0; ct < 4; ++ct){
    const int colc = (ct0+ct)*16 + lr;
    float badd = 0.f;
    if (OUTF32) badd = bias[colc];
    #pragma unroll
    for (int q = 0; q < 4; ++q){
      int row = orow0 + q;
      if (row < n){
        if (OUTF32) outf[(size_t)row*DD + colc] = acc[ct][q] + badd;
        else        outb[(size_t)row*DD + colc] = (__bf16)acc[ct][q];
      }
    }
  }
  if (!OUTF32){
    // attention logits from fp32 acc. Wave covers heads hA=ct0/2 (ct=0,1), hB=hA+1 (ct=2,3).
    float as4[4], ad4[4];
    #pragma unroll
    for (int ct = 0; ct < 4; ++ct){
      int colc = (ct0+ct)*16 + lr;
      as4[ct] = att_s[colc];
      ad4[ct] = att_d[colc];
    }
    float psA[4], psB[4], pdA[4], pdB[4];
    #pragma unroll
    for (int q = 0; q < 4; ++q){
      psA[q] = red16(acc[0][q]*as4[0] + acc[1][q]*as4[1]);
      psB[q] = red16(acc[2][q]*as4[2] + acc[3][q]*as4[3]);
      pdA[q] = red16(acc[0][q]*ad4[0] + acc[1][q]*ad4[1]);
      pdB[q] = red16(acc[2][q]*ad4[2] + acc[3][q]*ad4[3]);
    }
    if (lr == 0){
      const int hA = ct0 >> 1, hB = hA + 1;
      #pragma unroll
      for (int q = 0; q < 4; ++q){
        int row = orow0 + q;
        if (row < n){
          es[(size_t)hA*N + row] = psA[q];
          es[(size_t)hB*N + row] = psB[q];
          ed[(size_t)hA*N + row] = pdA[q];
          ed[(size_t)hB*N + row] = pdB[q];
        }
      }
    }
  }
}

// ---------------- aggregation + softmax(no-max) + bias + LN + relu + residual ----------------
// 1 wave per dst node; lane owns dims 2*lane, 2*lane+1 (head = lane>>4); unroll 4.
__global__ __launch_bounds__(256) void k_agg(const unsigned* __restrict__ xp,
    const float* __restrict__ es, const float* __restrict__ ed,
    const int* __restrict__ rowptr, const int* __restrict__ col,
    const float* __restrict__ cb, const float* __restrict__ lg, const float* __restrict__ lb,
    float* __restrict__ h, int n, int N)
{
  int wid = (blockIdx.x * blockDim.x + threadIdx.x) >> 6;
  int lane = threadIdx.x & 63;
  if (wid >= n) return;
  const int i = wid;
  const int rs = rowptr[i], re = rowptr[i+1];
  const int hsel = lane >> 4;
  const float* esh = es + (size_t)hsel*N;
  const float edd = ed[(size_t)hsel*N + i];
  float z = 0.f, a0 = 0.f, a1 = 0.f;
  int j = rs;
  for (; j + 4 <= re; j += 4){
    int s0 = col[j], s1 = col[j+1], s2 = col[j+2], s3 = col[j+3];
    float e0 = esh[s0], e1 = esh[s1], e2 = esh[s2], e3 = esh[s3];
    unsigned u0 = xp[(size_t)s0*64 + lane];
    unsigned u1 = xp[(size_t)s1*64 + lane];
    unsigned u2 = xp[(size_t)s2*64 + lane];
    unsigned u3 = xp[(size_t)s3*64 + lane];
    float w0 = __expf(lrelu(e0 + edd));
    float w1 = __expf(lrelu(e1 + edd));
    float w2 = __expf(lrelu(e2 + edd));
    float w3 = __expf(lrelu(e3 + edd));
    z += (w0 + w1) + (w2 + w3);
    a0 = fmaf(bflo(u0), w0, a0); a1 = fmaf(bfhi(u0), w0, a1);
    a0 = fmaf(bflo(u1), w1, a0); a1 = fmaf(bfhi(u1), w1, a1);
    a0 = fmaf(bflo(u2), w2, a0); a1 = fmaf(bfhi(u2), w2, a1);
    a0 = fmaf(bflo(u3), w3, a0); a1 = fmaf(bfhi(u3), w3, a1);
  }
  for (; j < re; ++j){
    int s = col[j];
    float w = __expf(lrelu(esh[s] + edd));
    unsigned u = xp[(size_t)s*64 + lane];
    z += w;
    a0 = fmaf(bflo(u), w, a0); a1 = fmaf(bfhi(u), w, a1);
  }
  float zi = 1.f / z;
  float2 cbv = *(const float2*)(cb + 2*lane);
  float c0 = a0*zi + cbv.x;
  float c1 = a1*zi + cbv.y;
  // LayerNorm over 128 dims (2 per lane)
  float sum = c0 + c1, sq = c0*c0 + c1*c1;
  #pragma unroll
  for (int off = 1; off < 64; off <<= 1){
    sum += __shfl_xor(sum, off);
    sq  += __shfl_xor(sq,  off);
  }
  float mu  = sum * (1.f/128.f);
  float var = sq  * (1.f/128.f) - mu*mu;
  float rinv = rsqrtf(var + 1e-5f);
  float2 lgv = *(const float2*)(lg + 2*lane);
  float2 lbv = *(const float2*)(lb + 2*lane);
  float y0 = (c0 - mu)*rinv*lgv.x + lbv.x;
  float y1 = (c1 - mu)*rinv*lgv.y + lbv.y;
  float2 rv = *(const float2*)(h + (size_t)i*DD + 2*lane);
  float2 o;
  o.x = fmaxf(y0, 0.f) + rv.x;
  o.y = fmaxf(y1, 0.f) + rv.y;
  *(float2*)(h + (size_t)i*DD + 2*lane) = o;
}

// ---------------- pooling (batch is sorted) ----------------
__global__ void k_pool(const float* __restrict__ h, const int* __restrict__ batch,
                       float* __restrict__ pooled, float* __restrict__ cnt, int n){
  int d = threadIdx.x; // 128 threads
  int n0 = blockIdx.x * 256;
  int n1 = min(n0 + 256, n);
  float acc = 0.f, cacc = 0.f; int cur = -1;
  for (int i = n0; i < n1; ++i){
    int g = batch[i];
    if (g != cur){
      if (cur >= 0){
        atomicAdd(&pooled[cur*DD + d], acc);
        if (d == 0) atomicAdd(&cnt[cur], cacc);
      }
      acc = 0.f; cacc = 0.f; cur = g;
    }
    acc += h[i*DD + d];
    cacc += 1.f;
  }
  if (cur >= 0){
    atomicAdd(&pooled[cur*DD + d], acc);
    if (d == 0) atomicAdd(&cnt[cur], cacc);
  }
}

// ---------------- final MLP ----------------
__global__ void k_mlp(const float* __restrict__ pooled, const float* __restrict__ cnt,
                      const float* __restrict__ W1, const float* __restrict__ b1,
                      const float* __restrict__ W2, const float* __restrict__ b2,
                      float* __restrict__ out, int G_){
  int g = blockIdx.x, lane = threadIdx.x; // 64 threads
  float inv = 1.f / fmaxf(cnt[g], 1.f);
  float acc = b1[lane];
  for (int k = 0; k < DD; ++k)
    acc = fmaf(pooled[g*DD + k]*inv, W1[k*64 + lane], acc);
  float hv = fmaxf(acc, 0.f) * W2[lane];
  #pragma unroll
  for (int off = 32; off; off >>= 1) hv += __shfl_down(hv, off);
  if (lane == 0) out[g] = hv + b2[0];
}

extern "C" void kernel_launch(void* const* d_in, const int* in_sizes, int n_in,
                              void* d_out, int out_size, void* d_ws, size_t ws_size,
                              hipStream_t stream){
  const float* x       = (const float*)d_in[0];
  const int*   ei      = (const int*)d_in[1];
  const int*   batch   = (const int*)d_in[2];
  const float* W_in    = (const float*)d_in[3];
  const float* b_in    = (const float*)d_in[4];
  const float* lin_W   = (const float*)d_in[5];
  const float* att_src = (const float*)d_in[6];
  const float* att_dst = (const float*)d_in[7];
  const float* conv_b  = (const float*)d_in[8];
  const float* ln_g    = (const float*)d_in[9];
  const float* ln_b    = (const float*)d_in[10];
  const float* W1      = (const float*)d_in[11];
  const float* b1      = (const float*)d_in[12];
  const float* W2      = (const float*)d_in[13];
  const float* b2      = (const float*)d_in[14];
  float* outp = (float*)d_out;

  const int N = in_sizes[0] / DD;
  const int E = in_sizes[1] / 2;
  const int G = out_size;
  const int L = 3;
  const int* srcp = ei;
  const int* dstp = ei + E;

  size_t off = 0;
  auto alloc = [&](size_t bytes) -> void* {
    void* p = (char*)d_ws + off;
    off += (bytes + 255) & ~(size_t)255;
    return p;
  };
  float*  h      = (float*) alloc((size_t)N*DD*4);
  __bf16* xhb    = (__bf16*)alloc((size_t)N*DD*2);
  float*  es     = (float*) alloc((size_t)N*4*4);   // head-major [4][N]
  float*  ed     = (float*) alloc((size_t)N*4*4);   // head-major [4][N]
  int*    deg    = (int*)   alloc((size_t)N*4);
  int*    rowptr = (int*)   alloc((size_t)(N+1)*4);
  int*    wptr   = (int*)   alloc((size_t)(N+1)*4);
  int*    col    = (int*)   alloc((size_t)(E+N)*4);
  int*    partial= (int*)   alloc(512*4);
  __bf16* wt     = (__bf16*)alloc((size_t)8*DD*DD*2); // 4 matrices x {hi,lo} planes
  float*  pooled = (float*) alloc((size_t)G*DD*4);
  float*  cnt    = (float*) alloc((size_t)G*4);

  const int nChunks = (N + 127)/128;

  // CSR build
  k_deg_init<<<(N+255)/256, 256, 0, stream>>>(deg, N);
  k_deg_hist<<<(E+255)/256, 256, 0, stream>>>(dstp, deg, E);
  k_scan_partial<<<nChunks, 128, 0, stream>>>(deg, partial, N);
  k_scan_top<<<1, 512, 0, stream>>>(partial, nChunks);
  k_scan_final<<<nChunks, 128, 0, stream>>>(deg, partial, rowptr, wptr, N);
  k_scatter<<<(E+N+255)/256, 256, 0, stream>>>(srcp, dstp, wptr, col, E, N);

  // weight prep (bf16 hi/lo transposed)
  k_wprep<<<256, 256, 0, stream>>>(W_in, lin_W, wt);

  // input projection (f32 out + bias)
  k_mm_mfma<1><<<(N+31)/32, 256, 0, stream>>>(x, wt, b_in, h, nullptr,
                                              nullptr, nullptr, nullptr, nullptr, N, N);

  // layers
  for (int l = 0; l < L; ++l){
    k_mm_mfma<0><<<(N+31)/32, 256, 0, stream>>>(h, wt + (size_t)2*(1+l)*DD*DD, nullptr,
                                                nullptr, xhb,
                                                att_src + l*DD, att_dst + l*DD, es, ed, N, N);
    k_agg<<<(N+3)/4, 256, 0, stream>>>((const unsigned*)xhb, es, ed, rowptr, col,
                                       conv_b + l*DD, ln_g + l*DD, ln_b + l*DD, h, N, N);
  }

  // pooling + MLP
  hipMemsetAsync(pooled, 0, (size_t)G*DD*4, stream);
  hipMemsetAsync(cnt,    0, (size_t)G*4,    stream);
  k_pool<<<(N+255)/256, 128, 0, stream>>>(h, batch, pooled, cnt, N);
  k_mlp<<<G, 64, 0, stream>>>(pooled, cnt, W1, b1, W2, b2, outp, G);
}

// Round 6
// 547.931 us; speedup vs baseline: 1.9196x; 1.0412x over previous
//
#include <hip/hip_runtime.h>

#define DD 128

typedef __bf16 bf16x8 __attribute__((ext_vector_type(8)));
typedef float  f32x4  __attribute__((ext_vector_type(4)));

__device__ __forceinline__ float lrelu(float x){ return x >= 0.f ? x : 0.2f*x; }
__device__ __forceinline__ float bflo(unsigned u){ return __uint_as_float(u << 16); }
__device__ __forceinline__ float bfhi(unsigned u){ return __uint_as_float(u & 0xffff0000u); }
__device__ __forceinline__ float red16(float v){
  v += __shfl_xor(v,1); v += __shfl_xor(v,2);
  v += __shfl_xor(v,4); v += __shfl_xor(v,8);
  return v;
}

// ---------------- CSR build ----------------
__global__ void k_deg_init(int* deg, int n){
  int i = blockIdx.x*blockDim.x + threadIdx.x;
  if (i < n) deg[i] = 1; // self loop
}
__global__ void k_deg_hist(const int* __restrict__ dst, int* __restrict__ deg, int E){
  int e = blockIdx.x*blockDim.x + threadIdx.x;
  if (e < E) atomicAdd(&deg[dst[e]], 1);
}
__global__ void k_scan_partial(const int* __restrict__ deg, int* __restrict__ partial, int n){
  __shared__ int s[128];
  int i = blockIdx.x*128 + threadIdx.x;
  int v = (i < n) ? deg[i] : 0;
  s[threadIdx.x] = v; __syncthreads();
  for (int off = 64; off; off >>= 1){
    if (threadIdx.x < off) s[threadIdx.x] += s[threadIdx.x + off];
    __syncthreads();
  }
  if (threadIdx.x == 0) partial[blockIdx.x] = s[0];
}
__global__ void k_scan_top(int* partial, int nChunks){
  __shared__ int s[512];
  int v = (threadIdx.x < nChunks) ? partial[threadIdx.x] : 0;
  s[threadIdx.x] = v; __syncthreads();
  for (int off = 1; off < 512; off <<= 1){
    int t = (threadIdx.x >= (unsigned)off) ? s[threadIdx.x - off] : 0;
    __syncthreads();
    s[threadIdx.x] += t;
    __syncthreads();
  }
  if (threadIdx.x < nChunks) partial[threadIdx.x] = s[threadIdx.x] - v; // exclusive
}
__global__ void k_scan_final(const int* __restrict__ deg, const int* __restrict__ partial,
                             int* __restrict__ rowptr, int* __restrict__ wptr, int n){
  __shared__ int s[128];
  int i = blockIdx.x*128 + threadIdx.x;
  int v = (i < n) ? deg[i] : 0;
  s[threadIdx.x] = v; __syncthreads();
  for (int off = 1; off < 128; off <<= 1){
    int t = (threadIdx.x >= (unsigned)off) ? s[threadIdx.x - off] : 0;
    __syncthreads();
    s[threadIdx.x] += t;
    __syncthreads();
  }
  int excl = s[threadIdx.x] - v + partial[blockIdx.x];
  if (i < n){
    rowptr[i] = excl; wptr[i] = excl;
    if (i == n-1) rowptr[n] = excl + v;
  }
}
__global__ void k_scatter(const int* __restrict__ src, const int* __restrict__ dst,
                          int* __restrict__ wptr, int* __restrict__ col, int E, int n){
  int e = blockIdx.x*blockDim.x + threadIdx.x;
  if (e < E){
    int d = dst[e];
    int p = atomicAdd(&wptr[d], 1);
    col[p] = src[e];
  } else if (e < E + n){
    int i = e - E;
    int p = atomicAdd(&wptr[i], 1);
    col[p] = i;
  }
}

// ---------------- weight prep: bf16 hi/lo col-major (B^T) for MFMA ----------------
__global__ void k_wprep(const float* __restrict__ Win, const float* __restrict__ linW,
                        __bf16* __restrict__ wt){
  int idx = blockIdx.x*256 + threadIdx.x;     // 4 * 16384 threads
  int m = idx >> 14, r = idx & 16383;
  int k = r >> 7, c = r & 127;
  const float* src = (m == 0) ? Win : linW + (size_t)(m-1)*DD*DD;
  float w = src[(size_t)k*DD + c];
  __bf16 hi = (__bf16)w;
  __bf16 lo = (__bf16)(w - (float)hi);
  wt[(size_t)(2*m  )*DD*DD + (size_t)c*DD + k] = hi;
  wt[(size_t)(2*m+1)*DD*DD + (size_t)c*DD + k] = lo;
}

// ---------------- MFMA matmul (3-term hi/lo): out = hin @ W (+bias) ----------------
template<int OUTF32>
__global__ __launch_bounds__(256) void k_mm_mfma(const float* __restrict__ hin,
    const __bf16* __restrict__ Wt, const float* __restrict__ bias,
    float* __restrict__ outf, __bf16* __restrict__ outb,
    const float* __restrict__ att_s, const float* __restrict__ att_d,
    float* __restrict__ es, float* __restrict__ ed, int n, int N)
{
  const int tid = threadIdx.x;
  const int wv  = tid >> 6, l = tid & 63;
  const int lr = l & 15, lk = l >> 4;
  const int row0 = blockIdx.x*32 + (wv >> 1)*16;
  const int ct0  = (wv & 1)*4;
  int arow = row0 + lr; if (arow >= n) arow = n - 1;
  const float* hp = hin + (size_t)arow*DD + lk*8;
  bf16x8 ah[4], al[4];
  #pragma unroll
  for (int kc = 0; kc < 4; ++kc){
    float4 lo4 = *(const float4*)(hp + kc*32);
    float4 hi4 = *(const float4*)(hp + kc*32 + 4);
    float vv[8] = {lo4.x,lo4.y,lo4.z,lo4.w,hi4.x,hi4.y,hi4.z,hi4.w};
    bf16x8 vh, vl;
    #pragma unroll
    for (int q = 0; q < 8; ++q){
      __bf16 h = (__bf16)vv[q];
      vh[q] = h;
      vl[q] = (__bf16)(vv[q] - (float)h);
    }
    ah[kc] = vh; al[kc] = vl;
  }
  f32x4 acc[4];
  #pragma unroll
  for (int ct = 0; ct < 4; ++ct) acc[ct] = (f32x4){0.f,0.f,0.f,0.f};
  const __bf16* wp = Wt + (size_t)lr*DD + lk*8;
  #pragma unroll
  for (int ct = 0; ct < 4; ++ct){
    const __bf16* wpc = wp + (size_t)(ct0+ct)*16*DD;
    #pragma unroll
    for (int kc = 0; kc < 4; ++kc){
      bf16x8 bh = *(const bf16x8*)(wpc + (size_t)kc*32);
      bf16x8 bl = *(const bf16x8*)(wpc + DD*DD + (size_t)kc*32);
      acc[ct] = __builtin_amdgcn_mfma_f32_16x16x32_bf16(ah[kc], bh, acc[ct], 0, 0, 0);
      acc[ct] = __builtin_amdgcn_mfma_f32_16x16x32_bf16(al[kc], bh, acc[ct], 0, 0, 0);
      acc[ct] = __builtin_amdgcn_mfma_f32_16x16x32_bf16(ah[kc], bl, acc[ct], 0, 0, 0);
    }
  }
  const int orow0 = row0 + lk*4;
  #pragma unroll
  for (int ct = 0; ct < 4; ++ct){
    const int colc = (ct0+ct)*16 + lr;
    float badd = 0.f;
    if (OUTF32) badd = bias[colc];
    #pragma unroll
    for (int q = 0; q < 4; ++q){
      int row = orow0 + q;
      if (row < n){
        if (OUTF32) outf[(size_t)row*DD + colc] = acc[ct][q] + badd;
        else        outb[(size_t)row*DD + colc] = (__bf16)acc[ct][q];
      }
    }
  }
  if (!OUTF32){
    float as4[4], ad4[4];
    #pragma unroll
    for (int ct = 0; ct < 4; ++ct){
      int colc = (ct0+ct)*16 + lr;
      as4[ct] = att_s[colc];
      ad4[ct] = att_d[colc];
    }
    float psA[4], psB[4], pdA[4], pdB[4];
    #pragma unroll
    for (int q = 0; q < 4; ++q){
      psA[q] = red16(acc[0][q]*as4[0] + acc[1][q]*as4[1]);
      psB[q] = red16(acc[2][q]*as4[2] + acc[3][q]*as4[3]);
      pdA[q] = red16(acc[0][q]*ad4[0] + acc[1][q]*ad4[1]);
      pdB[q] = red16(acc[2][q]*ad4[2] + acc[3][q]*ad4[3]);
    }
    if (lr == 0){
      const int hA = ct0 >> 1, hB = hA + 1;
      #pragma unroll
      for (int q = 0; q < 4; ++q){
        int row = orow0 + q;
        if (row < n){
          es[(size_t)hA*N + row] = psA[q];
          es[(size_t)hB*N + row] = psB[q];
          ed[(size_t)hA*N + row] = pdA[q];
          ed[(size_t)hB*N + row] = pdB[q];
        }
      }
    }
  }
}

// ---------------- aggregation + softmax(no-max) + bias + LN + relu + residual ----------------
// 1 wave per dst node; lane owns dims 2*lane, 2*lane+1 (head = lane>>4); unroll 8.
__global__ __launch_bounds__(256) void k_agg(const unsigned* __restrict__ xp,
    const float* __restrict__ es, const float* __restrict__ ed,
    const int* __restrict__ rowptr, const int* __restrict__ col,
    const float* __restrict__ cb, const float* __restrict__ lg, const float* __restrict__ lb,
    float* __restrict__ h, int n, int N)
{
  int wid = (blockIdx.x * blockDim.x + threadIdx.x) >> 6;
  int lane = threadIdx.x & 63;
  if (wid >= n) return;
  const int i = wid;
  const int rs = rowptr[i], re = rowptr[i+1];
  const int hsel = lane >> 4;
  const float* esh = es + (size_t)hsel*N;
  const float edd = ed[(size_t)hsel*N + i];
  float z = 0.f, a0 = 0.f, a1 = 0.f;
  int j = rs;
  for (; j + 8 <= re; j += 8){
    int s[8]; float e[8]; unsigned u[8]; float w[8];
    #pragma unroll
    for (int q = 0; q < 8; ++q) s[q] = col[j+q];
    #pragma unroll
    for (int q = 0; q < 8; ++q) e[q] = esh[s[q]];
    #pragma unroll
    for (int q = 0; q < 8; ++q) u[q] = xp[(size_t)s[q]*64 + lane];
    #pragma unroll
    for (int q = 0; q < 8; ++q) w[q] = __expf(lrelu(e[q] + edd));
    #pragma unroll
    for (int q = 0; q < 8; ++q){
      z += w[q];
      a0 = fmaf(bflo(u[q]), w[q], a0);
      a1 = fmaf(bfhi(u[q]), w[q], a1);
    }
  }
  for (; j < re; ++j){
    int s = col[j];
    float w = __expf(lrelu(esh[s] + edd));
    unsigned u = xp[(size_t)s*64 + lane];
    z += w;
    a0 = fmaf(bflo(u), w, a0); a1 = fmaf(bfhi(u), w, a1);
  }
  float zi = 1.f / z;
  float2 cbv = *(const float2*)(cb + 2*lane);
  float c0 = a0*zi + cbv.x;
  float c1 = a1*zi + cbv.y;
  // LayerNorm over 128 dims (2 per lane)
  float sum = c0 + c1, sq = c0*c0 + c1*c1;
  #pragma unroll
  for (int off = 1; off < 64; off <<= 1){
    sum += __shfl_xor(sum, off);
    sq  += __shfl_xor(sq,  off);
  }
  float mu  = sum * (1.f/128.f);
  float var = sq  * (1.f/128.f) - mu*mu;
  float rinv = rsqrtf(var + 1e-5f);
  float2 lgv = *(const float2*)(lg + 2*lane);
  float2 lbv = *(const float2*)(lb + 2*lane);
  float y0 = (c0 - mu)*rinv*lgv.x + lbv.x;
  float y1 = (c1 - mu)*rinv*lgv.y + lbv.y;
  float2 rv = *(const float2*)(h + (size_t)i*DD + 2*lane);
  float2 o;
  o.x = fmaxf(y0, 0.f) + rv.x;
  o.y = fmaxf(y1, 0.f) + rv.y;
  *(float2*)(h + (size_t)i*DD + 2*lane) = o;
}

// ---------------- pooling (batch sorted): 8 nodes/block, 6250 blocks ----------------
__global__ void k_pool(const float* __restrict__ h, const int* __restrict__ batch,
                       float* __restrict__ pooled, float* __restrict__ cnt, int n){
  int d = threadIdx.x; // 128 threads
  int n0 = blockIdx.x * 8;
  if (n0 >= n) return;
  int n1 = min(n0 + 8, n);
  float acc = 0.f, cacc = 0.f; int cur = batch[n0];
  for (int i = n0; i < n1; ++i){
    int g = batch[i];
    float v = h[(size_t)i*DD + d];
    if (g != cur){
      atomicAdd(&pooled[cur*DD + d], acc);
      if (d == 0) atomicAdd(&cnt[cur], cacc);
      acc = 0.f; cacc = 0.f; cur = g;
    }
    acc += v;
    cacc += 1.f;
  }
  atomicAdd(&pooled[cur*DD + d], acc);
  if (d == 0) atomicAdd(&cnt[cur], cacc);
}

// ---------------- final MLP ----------------
__global__ void k_mlp(const float* __restrict__ pooled, const float* __restrict__ cnt,
                      const float* __restrict__ W1, const float* __restrict__ b1,
                      const float* __restrict__ W2, const float* __restrict__ b2,
                      float* __restrict__ out, int G_){
  int g = blockIdx.x, lane = threadIdx.x; // 64 threads
  float inv = 1.f / fmaxf(cnt[g], 1.f);
  float acc = b1[lane];
  for (int k = 0; k < DD; ++k)
    acc = fmaf(pooled[g*DD + k]*inv, W1[k*64 + lane], acc);
  float hv = fmaxf(acc, 0.f) * W2[lane];
  #pragma unroll
  for (int off = 32; off; off >>= 1) hv += __shfl_down(hv, off);
  if (lane == 0) out[g] = hv + b2[0];
}

extern "C" void kernel_launch(void* const* d_in, const int* in_sizes, int n_in,
                              void* d_out, int out_size, void* d_ws, size_t ws_size,
                              hipStream_t stream){
  const float* x       = (const float*)d_in[0];
  const int*   ei      = (const int*)d_in[1];
  const int*   batch   = (const int*)d_in[2];
  const float* W_in    = (const float*)d_in[3];
  const float* b_in    = (const float*)d_in[4];
  const float* lin_W   = (const float*)d_in[5];
  const float* att_src = (const float*)d_in[6];
  const float* att_dst = (const float*)d_in[7];
  const float* conv_b  = (const float*)d_in[8];
  const float* ln_g    = (const float*)d_in[9];
  const float* ln_b    = (const float*)d_in[10];
  const float* W1      = (const float*)d_in[11];
  const float* b1      = (const float*)d_in[12];
  const float* W2      = (const float*)d_in[13];
  const float* b2      = (const float*)d_in[14];
  float* outp = (float*)d_out;

  const int N = in_sizes[0] / DD;
  const int E = in_sizes[1] / 2;
  const int G = out_size;
  const int L = 3;
  const int* srcp = ei;
  const int* dstp = ei + E;

  size_t off = 0;
  auto alloc = [&](size_t bytes) -> void* {
    void* p = (char*)d_ws + off;
    off += (bytes + 255) & ~(size_t)255;
    return p;
  };
  float*  h      = (float*) alloc((size_t)N*DD*4);
  __bf16* xhb    = (__bf16*)alloc((size_t)N*DD*2);
  float*  es     = (float*) alloc((size_t)N*4*4);   // head-major [4][N]
  float*  ed     = (float*) alloc((size_t)N*4*4);   // head-major [4][N]
  int*    deg    = (int*)   alloc((size_t)N*4);
  int*    rowptr = (int*)   alloc((size_t)(N+1)*4);
  int*    wptr   = (int*)   alloc((size_t)(N+1)*4);
  int*    col    = (int*)   alloc((size_t)(E+N)*4);
  int*    partial= (int*)   alloc(512*4);
  __bf16* wt     = (__bf16*)alloc((size_t)8*DD*DD*2); // 4 matrices x {hi,lo} planes
  float*  pooled = (float*) alloc((size_t)G*DD*4);
  float*  cnt    = (float*) alloc((size_t)G*4);

  const int nChunks = (N + 127)/128;

  // CSR build
  k_deg_init<<<(N+255)/256, 256, 0, stream>>>(deg, N);
  k_deg_hist<<<(E+255)/256, 256, 0, stream>>>(dstp, deg, E);
  k_scan_partial<<<nChunks, 128, 0, stream>>>(deg, partial, N);
  k_scan_top<<<1, 512, 0, stream>>>(partial, nChunks);
  k_scan_final<<<nChunks, 128, 0, stream>>>(deg, partial, rowptr, wptr, N);
  k_scatter<<<(E+N+255)/256, 256, 0, stream>>>(srcp, dstp, wptr, col, E, N);

  // weight prep (bf16 hi/lo transposed)
  k_wprep<<<256, 256, 0, stream>>>(W_in, lin_W, wt);

  // input projection (f32 out + bias)
  k_mm_mfma<1><<<(N+31)/32, 256, 0, stream>>>(x, wt, b_in, h, nullptr,
                                              nullptr, nullptr, nullptr, nullptr, N, N);

  // layers
  for (int l = 0; l < L; ++l){
    k_mm_mfma<0><<<(N+31)/32, 256, 0, stream>>>(h, wt + (size_t)2*(1+l)*DD*DD, nullptr,
                                                nullptr, xhb,
                                                att_src + l*DD, att_dst + l*DD, es, ed, N, N);
    k_agg<<<(N+3)/4, 256, 0, stream>>>((const unsigned*)xhb, es, ed, rowptr, col,
                                       conv_b + l*DD, ln_g + l*DD, ln_b + l*DD, h, N, N);
  }

  // pooling + MLP
  hipMemsetAsync(pooled, 0, (size_t)G*DD*4, stream);
  hipMemsetAsync(cnt,    0, (size_t)G*4,    stream);
  k_pool<<<(N+7)/8, 128, 0, stream>>>(h, batch, pooled, cnt, N);
  k_mlp<<<G, 64, 0, stream>>>(pooled, cnt, W1, b1, W2, b2, outp, G);
}

// Round 7
// 534.356 us; speedup vs baseline: 1.9683x; 1.0254x over previous
//
#include <hip/hip_runtime.h>

#define DD 128

typedef __bf16 bf16x8 __attribute__((ext_vector_type(8)));
typedef float  f32x4  __attribute__((ext_vector_type(4)));

__device__ __forceinline__ float lrelu(float x){ return x >= 0.f ? x : 0.2f*x; }
__device__ __forceinline__ float bflo(unsigned u){ return __uint_as_float(u << 16); }
__device__ __forceinline__ float bfhi(unsigned u){ return __uint_as_float(u & 0xffff0000u); }
__device__ __forceinline__ float red16(float v){
  v += __shfl_xor(v,1); v += __shfl_xor(v,2);
  v += __shfl_xor(v,4); v += __shfl_xor(v,8);
  return v;
}

// ---------------- CSR build ----------------
__global__ void k_deg_init(int* deg, int n){
  int i = blockIdx.x*blockDim.x + threadIdx.x;
  if (i < n) deg[i] = 1; // self loop
}
__global__ void k_deg_hist(const int* __restrict__ dst, int* __restrict__ deg, int E){
  int base = (blockIdx.x*blockDim.x + threadIdx.x)*4;
  if (base + 4 <= E){
    int4 d = *(const int4*)(dst + base);
    atomicAdd(&deg[d.x], 1);
    atomicAdd(&deg[d.y], 1);
    atomicAdd(&deg[d.z], 1);
    atomicAdd(&deg[d.w], 1);
  } else {
    for (int e = base; e < E; ++e) atomicAdd(&deg[dst[e]], 1);
  }
}
__global__ void k_scan_partial(const int* __restrict__ deg, int* __restrict__ partial, int n){
  __shared__ int s[128];
  int i = blockIdx.x*128 + threadIdx.x;
  int v = (i < n) ? deg[i] : 0;
  s[threadIdx.x] = v; __syncthreads();
  for (int off = 64; off; off >>= 1){
    if (threadIdx.x < off) s[threadIdx.x] += s[threadIdx.x + off];
    __syncthreads();
  }
  if (threadIdx.x == 0) partial[blockIdx.x] = s[0];
}
__global__ void k_scan_top(int* partial, int nChunks){
  __shared__ int s[512];
  int v = (threadIdx.x < nChunks) ? partial[threadIdx.x] : 0;
  s[threadIdx.x] = v; __syncthreads();
  for (int off = 1; off < 512; off <<= 1){
    int t = (threadIdx.x >= (unsigned)off) ? s[threadIdx.x - off] : 0;
    __syncthreads();
    s[threadIdx.x] += t;
    __syncthreads();
  }
  if (threadIdx.x < nChunks) partial[threadIdx.x] = s[threadIdx.x] - v; // exclusive
}
__global__ void k_scan_final(const int* __restrict__ deg, const int* __restrict__ partial,
                             int* __restrict__ rowptr, int* __restrict__ wptr, int n){
  __shared__ int s[128];
  int i = blockIdx.x*128 + threadIdx.x;
  int v = (i < n) ? deg[i] : 0;
  s[threadIdx.x] = v; __syncthreads();
  for (int off = 1; off < 128; off <<= 1){
    int t = (threadIdx.x >= (unsigned)off) ? s[threadIdx.x - off] : 0;
    __syncthreads();
    s[threadIdx.x] += t;
    __syncthreads();
  }
  int excl = s[threadIdx.x] - v + partial[blockIdx.x];
  if (i < n){
    rowptr[i] = excl; wptr[i] = excl;
    if (i == n-1) rowptr[n] = excl + v;
  }
}
// 4 edges per thread: 4 independent atomic chains in flight
__global__ void k_scatter(const int* __restrict__ src, const int* __restrict__ dst,
                          int* __restrict__ wptr, int* __restrict__ col, int E, int n){
  const int total = E + n;
  int base = (blockIdx.x*blockDim.x + threadIdx.x)*4;
  if (base >= total) return;
  int d[4], s[4]; bool ok[4];
  if (base + 4 <= E){
    int4 dv = *(const int4*)(dst + base);
    int4 sv = *(const int4*)(src + base);
    d[0]=dv.x; d[1]=dv.y; d[2]=dv.z; d[3]=dv.w;
    s[0]=sv.x; s[1]=sv.y; s[2]=sv.z; s[3]=sv.w;
    ok[0]=ok[1]=ok[2]=ok[3]=true;
  } else {
    #pragma unroll
    for (int q = 0; q < 4; ++q){
      int e = base + q;
      ok[q] = e < total;
      if (!ok[q]){ d[q]=0; s[q]=0; }
      else if (e < E){ d[q]=dst[e]; s[q]=src[e]; }
      else { d[q]=e-E; s[q]=e-E; }
    }
  }
  int p[4];
  #pragma unroll
  for (int q = 0; q < 4; ++q) if (ok[q]) p[q] = atomicAdd(&wptr[d[q]], 1);
  #pragma unroll
  for (int q = 0; q < 4; ++q) if (ok[q]) col[p[q]] = s[q];
}

// ---------------- weight prep: bf16 hi/lo col-major (B^T) for MFMA ----------------
__global__ void k_wprep(const float* __restrict__ Win, const float* __restrict__ linW,
                        __bf16* __restrict__ wt){
  int idx = blockIdx.x*256 + threadIdx.x;     // 4 * 16384 threads
  int m = idx >> 14, r = idx & 16383;
  int k = r >> 7, c = r & 127;
  const float* src = (m == 0) ? Win : linW + (size_t)(m-1)*DD*DD;
  float w = src[(size_t)k*DD + c];
  __bf16 hi = (__bf16)w;
  __bf16 lo = (__bf16)(w - (float)hi);
  wt[(size_t)(2*m  )*DD*DD + (size_t)c*DD + k] = hi;
  wt[(size_t)(2*m+1)*DD*DD + (size_t)c*DD + k] = lo;
}

// ---------------- MFMA matmul (3-term hi/lo): out = hin @ W (+bias) ----------------
template<int OUTF32>
__global__ __launch_bounds__(256) void k_mm_mfma(const float* __restrict__ hin,
    const __bf16* __restrict__ Wt, const float* __restrict__ bias,
    float* __restrict__ outf, __bf16* __restrict__ outb,
    const float* __restrict__ att_s, const float* __restrict__ att_d,
    float* __restrict__ es, float* __restrict__ ed, int n, int N)
{
  const int tid = threadIdx.x;
  const int wv  = tid >> 6, l = tid & 63;
  const int lr = l & 15, lk = l >> 4;
  const int row0 = blockIdx.x*32 + (wv >> 1)*16;
  const int ct0  = (wv & 1)*4;
  int arow = row0 + lr; if (arow >= n) arow = n - 1;
  const float* hp = hin + (size_t)arow*DD + lk*8;
  bf16x8 ah[4], al[4];
  #pragma unroll
  for (int kc = 0; kc < 4; ++kc){
    float4 lo4 = *(const float4*)(hp + kc*32);
    float4 hi4 = *(const float4*)(hp + kc*32 + 4);
    float vv[8] = {lo4.x,lo4.y,lo4.z,lo4.w,hi4.x,hi4.y,hi4.z,hi4.w};
    bf16x8 vh, vl;
    #pragma unroll
    for (int q = 0; q < 8; ++q){
      __bf16 h = (__bf16)vv[q];
      vh[q] = h;
      vl[q] = (__bf16)(vv[q] - (float)h);
    }
    ah[kc] = vh; al[kc] = vl;
  }
  f32x4 acc[4];
  #pragma unroll
  for (int ct = 0; ct < 4; ++ct) acc[ct] = (f32x4){0.f,0.f,0.f,0.f};
  const __bf16* wp = Wt + (size_t)lr*DD + lk*8;
  #pragma unroll
  for (int ct = 0; ct < 4; ++ct){
    const __bf16* wpc = wp + (size_t)(ct0+ct)*16*DD;
    #pragma unroll
    for (int kc = 0; kc < 4; ++kc){
      bf16x8 bh = *(const bf16x8*)(wpc + (size_t)kc*32);
      bf16x8 bl = *(const bf16x8*)(wpc + DD*DD + (size_t)kc*32);
      acc[ct] = __builtin_amdgcn_mfma_f32_16x16x32_bf16(ah[kc], bh, acc[ct], 0, 0, 0);
      acc[ct] = __builtin_amdgcn_mfma_f32_16x16x32_bf16(al[kc], bh, acc[ct], 0, 0, 0);
      acc[ct] = __builtin_amdgcn_mfma_f32_16x16x32_bf16(ah[kc], bl, acc[ct], 0, 0, 0);
    }
  }
  const int orow0 = row0 + lk*4;
  #pragma unroll
  for (int ct = 0; ct < 4; ++ct){
    const int colc = (ct0+ct)*16 + lr;
    float badd = 0.f;
    if (OUTF32) badd = bias[colc];
    #pragma unroll
    for (int q = 0; q < 4; ++q){
      int row = orow0 + q;
      if (row < n){
        if (OUTF32) outf[(size_t)row*DD + colc] = acc[ct][q] + badd;
        else        outb[(size_t)row*DD + colc] = (__bf16)acc[ct][q];
      }
    }
  }
  if (!OUTF32){
    float as4[4], ad4[4];
    #pragma unroll
    for (int ct = 0; ct < 4; ++ct){
      int colc = (ct0+ct)*16 + lr;
      as4[ct] = att_s[colc];
      ad4[ct] = att_d[colc];
    }
    float psA[4], psB[4], pdA[4], pdB[4];
    #pragma unroll
    for (int q = 0; q < 4; ++q){
      psA[q] = red16(acc[0][q]*as4[0] + acc[1][q]*as4[1]);
      psB[q] = red16(acc[2][q]*as4[2] + acc[3][q]*as4[3]);
      pdA[q] = red16(acc[0][q]*ad4[0] + acc[1][q]*ad4[1]);
      pdB[q] = red16(acc[2][q]*ad4[2] + acc[3][q]*ad4[3]);
    }
    if (lr == 0){
      const int hA = ct0 >> 1, hB = hA + 1;
      #pragma unroll
      for (int q = 0; q < 4; ++q){
        int row = orow0 + q;
        if (row < n){
          es[(size_t)hA*N + row] = psA[q];
          es[(size_t)hB*N + row] = psB[q];
          ed[(size_t)hA*N + row] = pdA[q];
          ed[(size_t)hB*N + row] = pdB[q];
        }
      }
    }
  }
}

// ---------------- aggregation + softmax(no-max) + bias + LN + relu + residual ----------------
// 1 wave per dst node; lane owns dims 2*lane, 2*lane+1 (head = lane>>4).
// Predicated 8-wide chunks: all edges (incl. tail) get 8-deep load ILP.
__global__ __launch_bounds__(256) void k_agg(const unsigned* __restrict__ xp,
    const float* __restrict__ es, const float* __restrict__ ed,
    const int* __restrict__ rowptr, const int* __restrict__ col,
    const float* __restrict__ cb, const float* __restrict__ lg, const float* __restrict__ lb,
    float* __restrict__ h, int n, int N)
{
  int wid = (blockIdx.x * blockDim.x + threadIdx.x) >> 6;
  int lane = threadIdx.x & 63;
  if (wid >= n) return;
  const int i = wid;
  const int rs = rowptr[i], re = rowptr[i+1];
  const int hsel = lane >> 4;
  const float* esh = es + (size_t)hsel*N;
  const float edd = ed[(size_t)hsel*N + i];
  float z = 0.f, a0 = 0.f, a1 = 0.f;
  const int slast = col[re-1]; // always valid: >=1 self-loop per node
  for (int j = rs; j < re; j += 8){
    int s[8]; bool ok[8];
    #pragma unroll
    for (int q = 0; q < 8; ++q){
      int jq = j + q;
      ok[q] = jq < re;
      s[q] = ok[q] ? col[jq] : slast;
    }
    float e[8]; unsigned u[8];
    #pragma unroll
    for (int q = 0; q < 8; ++q) e[q] = esh[s[q]];
    #pragma unroll
    for (int q = 0; q < 8; ++q) u[q] = xp[(size_t)s[q]*64 + lane];
    #pragma unroll
    for (int q = 0; q < 8; ++q){
      float w = ok[q] ? __expf(lrelu(e[q] + edd)) : 0.f;
      z += w;
      a0 = fmaf(bflo(u[q]), w, a0);
      a1 = fmaf(bfhi(u[q]), w, a1);
    }
  }
  float zi = 1.f / z;
  float2 cbv = *(const float2*)(cb + 2*lane);
  float c0 = a0*zi + cbv.x;
  float c1 = a1*zi + cbv.y;
  // LayerNorm over 128 dims (2 per lane)
  float sum = c0 + c1, sq = c0*c0 + c1*c1;
  #pragma unroll
  for (int off = 1; off < 64; off <<= 1){
    sum += __shfl_xor(sum, off);
    sq  += __shfl_xor(sq,  off);
  }
  float mu  = sum * (1.f/128.f);
  float var = sq  * (1.f/128.f) - mu*mu;
  float rinv = rsqrtf(var + 1e-5f);
  float2 lgv = *(const float2*)(lg + 2*lane);
  float2 lbv = *(const float2*)(lb + 2*lane);
  float y0 = (c0 - mu)*rinv*lgv.x + lbv.x;
  float y1 = (c1 - mu)*rinv*lgv.y + lbv.y;
  float2 rv = *(const float2*)(h + (size_t)i*DD + 2*lane);
  float2 o;
  o.x = fmaxf(y0, 0.f) + rv.x;
  o.y = fmaxf(y1, 0.f) + rv.y;
  *(float2*)(h + (size_t)i*DD + 2*lane) = o;
}

// ---------------- pooling (batch sorted): 8 nodes/block ----------------
__global__ void k_pool(const float* __restrict__ h, const int* __restrict__ batch,
                       float* __restrict__ pooled, float* __restrict__ cnt, int n){
  int d = threadIdx.x; // 128 threads
  int n0 = blockIdx.x * 8;
  if (n0 >= n) return;
  int n1 = min(n0 + 8, n);
  float acc = 0.f, cacc = 0.f; int cur = batch[n0];
  for (int i = n0; i < n1; ++i){
    int g = batch[i];
    float v = h[(size_t)i*DD + d];
    if (g != cur){
      atomicAdd(&pooled[cur*DD + d], acc);
      if (d == 0) atomicAdd(&cnt[cur], cacc);
      acc = 0.f; cacc = 0.f; cur = g;
    }
    acc += v;
    cacc += 1.f;
  }
  atomicAdd(&pooled[cur*DD + d], acc);
  if (d == 0) atomicAdd(&cnt[cur], cacc);
}

// ---------------- final MLP ----------------
__global__ void k_mlp(const float* __restrict__ pooled, const float* __restrict__ cnt,
                      const float* __restrict__ W1, const float* __restrict__ b1,
                      const float* __restrict__ W2, const float* __restrict__ b2,
                      float* __restrict__ out, int G_){
  int g = blockIdx.x, lane = threadIdx.x; // 64 threads
  float inv = 1.f / fmaxf(cnt[g], 1.f);
  float acc = b1[lane];
  for (int k = 0; k < DD; ++k)
    acc = fmaf(pooled[g*DD + k]*inv, W1[k*64 + lane], acc);
  float hv = fmaxf(acc, 0.f) * W2[lane];
  #pragma unroll
  for (int off = 32; off; off >>= 1) hv += __shfl_down(hv, off);
  if (lane == 0) out[g] = hv + b2[0];
}

extern "C" void kernel_launch(void* const* d_in, const int* in_sizes, int n_in,
                              void* d_out, int out_size, void* d_ws, size_t ws_size,
                              hipStream_t stream){
  const float* x       = (const float*)d_in[0];
  const int*   ei      = (const int*)d_in[1];
  const int*   batch   = (const int*)d_in[2];
  const float* W_in    = (const float*)d_in[3];
  const float* b_in    = (const float*)d_in[4];
  const float* lin_W   = (const float*)d_in[5];
  const float* att_src = (const float*)d_in[6];
  const float* att_dst = (const float*)d_in[7];
  const float* conv_b  = (const float*)d_in[8];
  const float* ln_g    = (const float*)d_in[9];
  const float* ln_b    = (const float*)d_in[10];
  const float* W1      = (const float*)d_in[11];
  const float* b1      = (const float*)d_in[12];
  const float* W2      = (const float*)d_in[13];
  const float* b2      = (const float*)d_in[14];
  float* outp = (float*)d_out;

  const int N = in_sizes[0] / DD;
  const int E = in_sizes[1] / 2;
  const int G = out_size;
  const int L = 3;
  const int* srcp = ei;
  const int* dstp = ei + E;

  size_t off = 0;
  auto alloc = [&](size_t bytes) -> void* {
    void* p = (char*)d_ws + off;
    off += (bytes + 255) & ~(size_t)255;
    return p;
  };
  float*  h      = (float*) alloc((size_t)N*DD*4);
  __bf16* xhb    = (__bf16*)alloc((size_t)N*DD*2);
  float*  es     = (float*) alloc((size_t)N*4*4);   // head-major [4][N]
  float*  ed     = (float*) alloc((size_t)N*4*4);   // head-major [4][N]
  int*    deg    = (int*)   alloc((size_t)N*4);
  int*    rowptr = (int*)   alloc((size_t)(N+1)*4);
  int*    wptr   = (int*)   alloc((size_t)(N+1)*4);
  int*    col    = (int*)   alloc((size_t)(E+N)*4);
  int*    partial= (int*)   alloc(512*4);
  __bf16* wt     = (__bf16*)alloc((size_t)8*DD*DD*2); // 4 matrices x {hi,lo} planes
  float*  pooled = (float*) alloc((size_t)G*DD*4);
  float*  cnt    = (float*) alloc((size_t)G*4);

  const int nChunks = (N + 127)/128;

  // CSR build
  k_deg_init<<<(N+255)/256, 256, 0, stream>>>(deg, N);
  k_deg_hist<<<(E/4+255)/256, 256, 0, stream>>>(dstp, deg, E);
  k_scan_partial<<<nChunks, 128, 0, stream>>>(deg, partial, N);
  k_scan_top<<<1, 512, 0, stream>>>(partial, nChunks);
  k_scan_final<<<nChunks, 128, 0, stream>>>(deg, partial, rowptr, wptr, N);
  k_scatter<<<((E+N)/4+255)/256, 256, 0, stream>>>(srcp, dstp, wptr, col, E, N);

  // weight prep (bf16 hi/lo transposed)
  k_wprep<<<256, 256, 0, stream>>>(W_in, lin_W, wt);

  // input projection (f32 out + bias)
  k_mm_mfma<1><<<(N+31)/32, 256, 0, stream>>>(x, wt, b_in, h, nullptr,
                                              nullptr, nullptr, nullptr, nullptr, N, N);

  // layers
  for (int l = 0; l < L; ++l){
    k_mm_mfma<0><<<(N+31)/32, 256, 0, stream>>>(h, wt + (size_t)2*(1+l)*DD*DD, nullptr,
                                                nullptr, xhb,
                                                att_src + l*DD, att_dst + l*DD, es, ed, N, N);
    k_agg<<<(N+3)/4, 256, 0, stream>>>((const unsigned*)xhb, es, ed, rowptr, col,
                                       conv_b + l*DD, ln_g + l*DD, ln_b + l*DD, h, N, N);
  }

  // pooling + MLP
  hipMemsetAsync(pooled, 0, (size_t)G*DD*4, stream);
  hipMemsetAsync(cnt,    0, (size_t)G*4,    stream);
  k_pool<<<(N+7)/8, 128, 0, stream>>>(h, batch, pooled, cnt, N);
  k_mlp<<<G, 64, 0, stream>>>(pooled, cnt, W1, b1, W2, b2, outp, G);
}